// Round 10
// baseline (193.738 us; speedup 1.0000x reference)
//
#include <hip/hip_runtime.h>

// ---------------------------------------------------------------------------
// MultiHeadAttention forward, MI355X/gfx950.
// cvt(fp32->bf16, Wq pre-scaled by log2e/8) -> QKV proj (bf16 MFMA, XCD-swz)
// -> V transpose -> flash attn v9 (32x32 MFMA, permlane P-redistribution,
// KV-SPLIT x2: grid 1024 -> 4 blocks/CU, additive f32 partials via atomicAdd,
// no-max softmax) -> normalize -> out proj (XCD-swz).
// ---------------------------------------------------------------------------

#define DEV static __device__ __forceinline__

typedef unsigned short u16;
typedef __attribute__((ext_vector_type(8))) short short8;
typedef __attribute__((ext_vector_type(4))) float f32x4;
typedef __attribute__((ext_vector_type(16))) float f32x16;
typedef __attribute__((ext_vector_type(4))) unsigned short ushort4v;
typedef __attribute__((ext_vector_type(4))) unsigned int uint4v;

#define SEQ   2048
#define BATCH 2
#define DM    1024
#define NH    16
#define DKH   64
#define MROWS (SEQ*BATCH)   // 4096

DEV u16 f2bf(float f) {            // RNE
  union { float f; unsigned int u; } v; v.f = f;
  unsigned int u = v.u;
  return (u16)((u + 0x7FFFu + ((u >> 16) & 1u)) >> 16);
}

DEV unsigned int cvtpk_bf16(float lo, float hi) {  // dword = bf16(hi)<<16 | bf16(lo), RNE
  unsigned int r;
  asm("v_cvt_pk_bf16_f32 %0, %1, %2" : "=v"(r) : "v"(lo), "v"(hi));
  return r;
}

// v_permlane32_swap_b32 a, b: swaps a.lanes[32:63] <-> b.lanes[0:31]
DEV void permswap(unsigned int& a, unsigned int& b) {
  asm volatile("v_permlane32_swap_b32 %0, %1" : "+v"(a), "+v"(b));
}

#if __has_builtin(__builtin_amdgcn_exp2f)
#define EXP2(x) __builtin_amdgcn_exp2f(x)
#else
#define EXP2(x) exp2f(x)
#endif

// async global->LDS, 16B per lane. LDS dest is wave-uniform base + lane*16.
DEV void async16(const void* g, void* l) {
  __builtin_amdgcn_global_load_lds(
      (const __attribute__((address_space(1))) unsigned int*)g,
      (__attribute__((address_space(3))) unsigned int*)l, 16, 0, 0);
}

// ---------------------------------------------------------------------------
// fp32 -> bf16 conversion (grid.y = tensor id; y==7 is the mask-zero scan)
// ---------------------------------------------------------------------------
struct CvtArgs {
  const float* s[8];
  u16* d[8];
  int n[8];
  float scale[8];
  int* flag;
};

__global__ __launch_bounds__(256) void cvt_kernel(CvtArgs a) {
  const int t = blockIdx.y;
  const int n = a.n[t];
  const int stride = 1024 * 256 * 4;
  if (t == 7) {   // mask scan
    const float* __restrict__ m = a.s[7];
    int any = 0;
    for (int i = (blockIdx.x * 256 + threadIdx.x) * 4; i < n; i += stride) {
      f32x4 v = *(const f32x4*)&m[i];
      any |= (v[0] != 0.f); any |= (v[1] != 0.f);
      any |= (v[2] != 0.f); any |= (v[3] != 0.f);
    }
    if (any) atomicOr(a.flag, 1);
    return;
  }
  const float* __restrict__ s = a.s[t];
  u16* __restrict__ d = a.d[t];
  const float sc = a.scale[t];
  for (int i = (blockIdx.x * 256 + threadIdx.x) * 4; i < n; i += stride) {
    f32x4 f = *(const f32x4*)&s[i];
    ushort4v o;
    o[0] = f2bf(f[0] * sc); o[1] = f2bf(f[1] * sc);
    o[2] = f2bf(f[2] * sc); o[3] = f2bf(f[3] * sc);
    *(ushort4v*)&d[i] = o;
  }
}

// ---------------------------------------------------------------------------
// GEMM: C[M,N] = A[M,K] @ W[N,K]^T + bias*bscale.
// Block tile (MT*32) x (NT*32), BK=64, 4 waves in 2x2.
// ---------------------------------------------------------------------------
template <int MT, int NT, typename OutT>
DEV void gemm_body(const u16* __restrict__ A,
                   const u16* __restrict__ W,
                   const float* __restrict__ bias, float bscale,
                   OutT* __restrict__ C,
                   u16* As, u16* Bs,
                   int M, int N, int K, int m0, int n0) {
  const int tid = threadIdx.x;
  const int lane = tid & 63;
  const int wid = tid >> 6;
  const int wr = wid >> 1, wc = wid & 1;
  const int sr = lane & 15, g = lane >> 4;

  f32x4 acc[MT][NT] = {};

  const int arow = tid >> 3;          // 0..31
  const int acol = (tid & 7) * 8;     // elem col within 64
  const size_t abase = (size_t)(m0 + arow) * K + acol;
  const size_t bbase = (size_t)(n0 + arow) * K + acol;

  for (int kt = 0; kt < K; kt += 64) {
#pragma unroll
    for (int j = 0; j < MT; ++j)
      async16(A + abase + (size_t)j * 32 * K + kt, (char*)As + j * 4096 + wid * 1024);
#pragma unroll
    for (int j = 0; j < NT; ++j)
      async16(W + bbase + (size_t)j * 32 * K + kt, (char*)Bs + j * 4096 + wid * 1024);
    __syncthreads();
#pragma unroll
    for (int kk = 0; kk < 2; ++kk) {
      short8 af[MT], bf[NT];
#pragma unroll
      for (int mt = 0; mt < MT; ++mt)
        af[mt] = *(const short8*)&As[(wr * MT * 16 + mt * 16 + sr) * 64 + kk * 32 + g * 8];
#pragma unroll
      for (int nt = 0; nt < NT; ++nt)
        bf[nt] = *(const short8*)&Bs[(wc * NT * 16 + nt * 16 + sr) * 64 + kk * 32 + g * 8];
#pragma unroll
      for (int mt = 0; mt < MT; ++mt)
#pragma unroll
        for (int nt = 0; nt < NT; ++nt)
          acc[mt][nt] = __builtin_amdgcn_mfma_f32_16x16x32_bf16(af[mt], bf[nt], acc[mt][nt], 0, 0, 0);
    }
    __syncthreads();
  }

  // C/D layout: row=(lane>>4)*4+reg, col=lane&15  [m89-verified]
#pragma unroll
  for (int nt = 0; nt < NT; ++nt) {
    const int col = n0 + wc * NT * 16 + nt * 16 + sr;
    const float bv = bias[col] * bscale;
#pragma unroll
    for (int mt = 0; mt < MT; ++mt) {
#pragma unroll
      for (int r = 0; r < 4; ++r) {
        const int row = m0 + wr * MT * 16 + mt * 16 + g * 4 + r;
        const float val = acc[mt][nt][r] + bv;
        if constexpr (sizeof(OutT) == 2)
          C[(size_t)row * N + col] = f2bf(val);
        else
          C[(size_t)row * N + col] = val;
      }
    }
  }
}

struct GemmPtrs {
  const u16* A[3];
  const u16* W[3];
  const float* bias[3];
  float bscale[3];
  u16* C[3];
};

__global__ __launch_bounds__(256) void gemm_qkv_kernel(GemmPtrs p, int M, int N, int K) {
  __shared__ u16 As[128 * 64];
  __shared__ u16 Bs[128 * 64];
  const int z = blockIdx.z;
  const int fl = blockIdx.x + 32 * blockIdx.y;
  const int virt = (fl & 7) * 32 + (fl >> 3);
  const int mb = virt >> 3, nb = virt & 7;
  gemm_body<4, 4, u16>(p.A[z], p.W[z], p.bias[z], p.bscale[z], p.C[z], As, Bs,
                       M, N, K, mb * 128, nb * 128);
}

__global__ __launch_bounds__(256) void gemm_f32_kernel(const u16* __restrict__ A,
                                                       const u16* __restrict__ W,
                                                       const float* __restrict__ bias,
                                                       float* __restrict__ C,
                                                       int M, int N, int K) {
  __shared__ u16 As[64 * 64];
  __shared__ u16 Bs[128 * 64];
  const int fl = blockIdx.x + 64 * blockIdx.y;
  const int virt = (fl & 7) * 64 + (fl >> 3);
  const int mb = virt >> 3, nb = virt & 7;
  gemm_body<2, 4, float>(A, W, bias, 1.0f, C, As, Bs, M, N, K,
                         mb * 64, nb * 128);
}

// ---------------------------------------------------------------------------
// V transpose: Vh (S,B,D) bf16 -> VT[bh][dk][t]  (shape [32][64][2048])
// ---------------------------------------------------------------------------
__global__ __launch_bounds__(256) void vtrans_kernel(const u16* __restrict__ Vh,
                                                     u16* __restrict__ VT) {
  __shared__ u16 tl[4096];   // [t][dk] linear
  const int tid = threadIdx.x;
  const int w = tid >> 6;
  const int t0 = blockIdx.x * 64;
  const int bh = blockIdx.y;
  const int b = bh >> 4, h = bh & 15;
  const int str = tid >> 3;
  const int scc = (tid & 7) * 8;
#pragma unroll
  for (int it = 0; it < 2; ++it)
    async16(Vh + (size_t)((t0 + str + it * 32) * 2 + b) * 1024 + h * 64 + scc,
            (char*)tl + it * 4096 + w * 1024);
  __syncthreads();
  const int dk = tid >> 2;
  const int t4 = (tid & 3) * 16;
  short8 ov[2];
#pragma unroll
  for (int half = 0; half < 2; ++half)
#pragma unroll
    for (int j = 0; j < 8; ++j)
      ov[half][j] = (short)tl[(t4 + half * 8 + j) * 64 + dk];
  u16* dst = VT + (size_t)(bh * 64 + dk) * 2048 + t0 + t4;
  *(short8*)dst = ov[0];
  *(short8*)(dst + 8) = ov[1];
}

// ---------------------------------------------------------------------------
// Flash attention v9: 32x32x16 MFMA, KV-split x2.  Grid 1024 flat (XCD-
// swizzled; each XCD = 4 bh, all (qi, half)), 256 thr = 4 waves (4 blk/CU ->
// 4 waves/SIMD), wave owns 32 q-rows, t-range = half*1024..+1024, 16 tiles.
// Single-tile dbuf staging (32KB LDS).  Swapped QK^T (A=K, B=Q, 0.125*log2e
// in Wq); C/D col=q=lane&31, row t=(r&3)+8*(r>>2)+4*(lane>>5) [m74/m101].
// P->PV A-frags via cvt_pk + permswap (verified r8).  No-max softmax ->
// partials are ADDITIVE: atomicAdd f32 O_unnorm + l (exactly 2 commutative
// contributions per element -> deterministic).
// ---------------------------------------------------------------------------
__global__ __launch_bounds__(256, 4) void attn9_kernel(const u16* __restrict__ Q,
                                                       const u16* __restrict__ K,
                                                       const u16* __restrict__ VT,
                                                       const float* __restrict__ mask,
                                                       const int* __restrict__ maskflag,
                                                       float* __restrict__ Opart,
                                                       float* __restrict__ lpart) {
  __shared__ u16 Kl[2][4096];   // [t 0..63][d 0..63], 128B rows, XOR-swizzled
  __shared__ u16 Vl[2][4096];   // [d 0..63][t 0..63], 128B rows, XOR-swizzled

  const int tid = threadIdx.x;
  const int lane = tid & 63;
  const int w = tid >> 6;
  const int ln = lane & 31;     // col within 32-block
  const int hi = lane >> 5;     // lane half
  const int sw = (ln & 7) << 4;

  // XCD swizzle: 1024 = 8 XCDs x 128; each XCD gets 4 bh x (2 half x 16 qi)
  const int flat = blockIdx.x;
  const int virt = ((flat & 7) << 7) | (flat >> 3);
  const int bh = virt >> 5;
  const int half = (virt >> 4) & 1;
  const int qi = virt & 15;
  const int q0 = qi * 128 + w * 32;
  const int tbase = half * 1024;
  const int b = bh >> 4, h = bh & 15;
  const int usemask = *maskflag;

  const u16* Qb = Q + b * DM + h * DKH;
  const u16* Kb = K + b * DM + h * DKH;
  const u16* VTb = VT + (size_t)bh * 64 * 2048;

  // Q fragments (B-operand 32x32x16: col n=q=ln, k = ks*16 + hi*8 + j)
  short8 aq[4];
#pragma unroll
  for (int ks = 0; ks < 4; ++ks)
    aq[ks] = *(const short8*)&Qb[(size_t)(q0 + ln) * 2048 + ks * 16 + hi * 8];

  f32x16 acc[2] = {};
  float l_ = 0.f;
  const float L2E = 1.44269504088896f;

  const int strow = tid >> 3;                                   // 0..31
  const int scb = (((tid & 7) * 16) ^ ((strow & 7) << 4)) >> 1; // pre-swizzled col (elems)

  auto STAGE = [&](int nb, int t0n) {
#pragma unroll
    for (int it = 0; it < 2; ++it) {
      async16(Kb + (size_t)(t0n + strow + it * 32) * 2048 + scb,
              (char*)&Kl[nb][0] + it * 4096 + w * 1024);
      async16(VTb + (size_t)(strow + it * 32) * 2048 + t0n + scb,
              (char*)&Vl[nb][0] + it * 4096 + w * 1024);
    }
  };

  STAGE(0, tbase);
  __syncthreads();
  int cur = 0;

  for (int t0 = tbase; t0 < tbase + 1024; t0 += 64) {
    if (t0 + 64 < tbase + 1024) STAGE(cur ^ 1, t0 + 64);

    // K fragments (A-operand: row t = tb*32+ln, k = d = ks*16+hi*8+j)
    short8 kf[2][4];
#pragma unroll
    for (int tb = 0; tb < 2; ++tb)
#pragma unroll
      for (int ks = 0; ks < 4; ++ks)
        kf[tb][ks] = *(const short8*)((const char*)&Kl[cur][0] +
                                      (tb * 32 + ln) * 128 + ((ks * 32 + hi * 16) ^ sw));

    // S'^T (log2 units): 2 blocks of 32t x 32q
    f32x16 sc[2] = {};
    __builtin_amdgcn_s_setprio(1);
#pragma unroll
    for (int tb = 0; tb < 2; ++tb)
#pragma unroll
      for (int ks = 0; ks < 4; ++ks)
        sc[tb] = __builtin_amdgcn_mfma_f32_32x32x16_bf16(kf[tb][ks], aq[ks], sc[tb], 0, 0, 0);
    __builtin_amdgcn_s_setprio(0);

    // V^T fragments (B-operand: col n=d=db*32+ln, k = t = ks*16+hi*8+j)
    short8 vf[2][4];
#pragma unroll
    for (int db = 0; db < 2; ++db)
#pragma unroll
      for (int ks = 0; ks < 4; ++ks)
        vf[db][ks] = *(const short8*)((const char*)&Vl[cur][0] +
                                      (db * 32 + ln) * 128 + ((ks * 32 + hi * 16) ^ sw));

    // no-max softmax + in-register P redistribution (cvt_pk + permlane32_swap)
    short8 pa[4];
    float rs = 0.f;
#pragma unroll
    for (int tb = 0; tb < 2; ++tb) {
      float p[16];
#pragma unroll
      for (int r = 0; r < 16; ++r) {
        float xv = sc[tb][r];
        if (usemask)
          xv = __builtin_fmaf(
              mask[(size_t)(q0 + ln) * SEQ + t0 + tb * 32 + (r & 3) + 8 * (r >> 2) + 4 * hi],
              L2E, xv);
        p[r] = EXP2(xv);
        rs += p[r];
      }
#pragma unroll
      for (int ksl = 0; ksl < 2; ++ksl) {
        unsigned int c0 = cvtpk_bf16(p[8 * ksl + 0], p[8 * ksl + 1]);  // (t0,t1 | t4,t5)
        unsigned int c1 = cvtpk_bf16(p[8 * ksl + 2], p[8 * ksl + 3]);  // (t2,t3 | t6,t7)
        unsigned int c4 = cvtpk_bf16(p[8 * ksl + 4], p[8 * ksl + 5]);  // (t8,t9 | t12,t13)
        unsigned int c5 = cvtpk_bf16(p[8 * ksl + 6], p[8 * ksl + 7]);  // (t10,t11|t14,t15)
        permswap(c0, c4);   // c0 -> dword0; c4 -> dword2
        permswap(c1, c5);   // c1 -> dword1; c5 -> dword3
        union { uint4v u; short8 s; } cc;
        cc.u[0] = c0; cc.u[1] = c1; cc.u[2] = c4; cc.u[3] = c5;
        pa[tb * 2 + ksl] = cc.s;
      }
    }
    l_ += rs;

    // PV: O[q][d] += P[q][t] V[t][d]
    __builtin_amdgcn_s_setprio(1);
#pragma unroll
    for (int ks = 0; ks < 4; ++ks)
#pragma unroll
      for (int db = 0; db < 2; ++db)
        acc[db] = __builtin_amdgcn_mfma_f32_32x32x16_bf16(pa[ks], vf[db][ks], acc[db], 0, 0, 0);
    __builtin_amdgcn_s_setprio(0);
    __syncthreads();
    cur ^= 1;
  }

  // partial epilogue: combine lane halves of l, then atomicAdd partials
  l_ += __shfl_xor(l_, 32);
  if (lane < 32) atomicAdd(&lpart[bh * 2048 + q0 + ln], l_);
  const size_t obase = (size_t)b * DM + h * DKH;
#pragma unroll
  for (int db = 0; db < 2; ++db)
#pragma unroll
    for (int r = 0; r < 16; ++r) {
      const int q = q0 + (r & 3) + 8 * (r >> 2) + 4 * hi;
      atomicAdd(&Opart[(size_t)q * 2048 + obase + db * 32 + ln], acc[db][r]);
    }
}

// ---------------------------------------------------------------------------
// Normalize: AO[i] = bf16(Opart[i] / l[row]) over (S,B,D) f32 -> bf16
// ---------------------------------------------------------------------------
__global__ __launch_bounds__(256) void norm_kernel(const float* __restrict__ Opart,
                                                   const float* __restrict__ lpart,
                                                   u16* __restrict__ AO) {
  const int i4 = (blockIdx.x * 256 + threadIdx.x) * 4;
  const int row = i4 >> 10;          // q*2 + b
  const int col = i4 & 1023;         // h*64 + dk
  const int b = row & 1, q = row >> 1, h = col >> 6;
  const float l = lpart[(b * 16 + h) * 2048 + q];
  const float inv = 1.0f / l;
  f32x4 o = *(const f32x4*)&Opart[i4];
  ushort4v out;
  out[0] = f2bf(o[0] * inv); out[1] = f2bf(o[1] * inv);
  out[2] = f2bf(o[2] * inv); out[3] = f2bf(o[3] * inv);
  *(ushort4v*)&AO[i4] = out;
}

// ---------------------------------------------------------------------------
// Launch
// ---------------------------------------------------------------------------
extern "C" void kernel_launch(void* const* d_in, const int* in_sizes, int n_in,
                              void* d_out, int out_size, void* d_ws, size_t ws_size,
                              hipStream_t stream) {
  const float* q = (const float*)d_in[0];
  const float* k = (const float*)d_in[1];
  const float* v = (const float*)d_in[2];
  const float* msk = (const float*)d_in[3];
  const float* Wq = (const float*)d_in[4];
  const float* bq = (const float*)d_in[5];
  const float* Wk = (const float*)d_in[6];
  const float* bk = (const float*)d_in[7];
  const float* Wv = (const float*)d_in[8];
  const float* bv = (const float*)d_in[9];
  const float* Wo = (const float*)d_in[10];
  const float* bo = (const float*)d_in[11];
  float* out = (float*)d_out;

  char* ws = (char*)d_ws;
  const size_t SZX = (size_t)MROWS * DM * 2;   // 8 MB bf16 activation
  const size_t SZW = (size_t)DM * DM * 2;      // 2 MB bf16 weight
  u16* qb  = (u16*)(ws + 0 * SZX);
  u16* kb  = (u16*)(ws + 1 * SZX);
  u16* vb  = (u16*)(ws + 2 * SZX);
  u16* Wqb = (u16*)(ws + 3 * SZX + 0 * SZW);
  u16* Wkb = (u16*)(ws + 3 * SZX + 1 * SZW);
  u16* Wvb = (u16*)(ws + 3 * SZX + 2 * SZW);
  u16* Wob = (u16*)(ws + 3 * SZX + 3 * SZW);
  u16* Qh  = (u16*)(ws + 3 * SZX + 4 * SZW + 0 * SZX);
  u16* Kh  = (u16*)(ws + 3 * SZX + 4 * SZW + 1 * SZX);
  u16* Vh  = (u16*)(ws + 3 * SZX + 4 * SZW + 2 * SZX);
  u16* AO  = (u16*)(ws + 3 * SZX + 4 * SZW + 3 * SZX);
  int* flag = (int*)(ws + 7 * SZX + 4 * SZW);
  u16* VTg = qb;                 // reuse qb (dead after gemm_qkv)
  float* Opart = (float*)kb;     // reuse kb+vb (16 MB, dead after gemm_qkv)
  float* lpart = (float*)Wqb;    // reuse Wqb (256 KB needed, dead after gemm_qkv)

  hipMemsetAsync(flag, 0, 4, stream);

  // fold softmax scale AND log2(e) into Wq/bq: S' = (QK^T)/8 * log2e
  const float QS = 0.125f * 1.44269504088896f;

  CvtArgs ca;
  ca.s[0] = q;  ca.d[0] = qb;  ca.n[0] = MROWS * DM; ca.scale[0] = 1.f;
  ca.s[1] = k;  ca.d[1] = kb;  ca.n[1] = MROWS * DM; ca.scale[1] = 1.f;
  ca.s[2] = v;  ca.d[2] = vb;  ca.n[2] = MROWS * DM; ca.scale[2] = 1.f;
  ca.s[3] = Wq; ca.d[3] = Wqb; ca.n[3] = DM * DM;    ca.scale[3] = QS;
  ca.s[4] = Wk; ca.d[4] = Wkb; ca.n[4] = DM * DM;    ca.scale[4] = 1.f;
  ca.s[5] = Wv; ca.d[5] = Wvb; ca.n[5] = DM * DM;    ca.scale[5] = 1.f;
  ca.s[6] = Wo; ca.d[6] = Wob; ca.n[6] = DM * DM;    ca.scale[6] = 1.f;
  ca.s[7] = msk; ca.d[7] = nullptr; ca.n[7] = SEQ * SEQ; ca.scale[7] = 1.f;
  ca.flag = flag;
  cvt_kernel<<<dim3(1024, 8, 1), 256, 0, stream>>>(ca);

  GemmPtrs gp;
  gp.A[0] = qb; gp.W[0] = Wqb; gp.bias[0] = bq; gp.bscale[0] = QS;  gp.C[0] = Qh;
  gp.A[1] = kb; gp.W[1] = Wkb; gp.bias[1] = bk; gp.bscale[1] = 1.f; gp.C[1] = Kh;
  gp.A[2] = vb; gp.W[2] = Wvb; gp.bias[2] = bv; gp.bscale[2] = 1.f; gp.C[2] = Vh;
  gemm_qkv_kernel<<<dim3(32, 8, 3), 256, 0, stream>>>(gp, MROWS, DM, DM);

  vtrans_kernel<<<dim3(32, 32, 1), 256, 0, stream>>>(Vh, VTg);

  // zero the additive partial buffers (stream-ordered: after gemm_qkv frees kb/vb/Wqb)
  hipMemsetAsync(Opart, 0, (size_t)MROWS * DM * 4, stream);
  hipMemsetAsync(lpart, 0, 32 * 2048 * 4, stream);

  attn9_kernel<<<dim3(1024, 1, 1), 256, 0, stream>>>(Qh, Kh, VTg, msk, flag, Opart, lpart);

  norm_kernel<<<dim3(MROWS * DM / 1024, 1, 1), 256, 0, stream>>>(Opart, lpart, AO);

  gemm_f32_kernel<<<dim3(64, 8, 1), 256, 0, stream>>>(AO, Wob, bo, out, MROWS, DM, DM);
}

// Round 11
// 174.630 us; speedup vs baseline: 1.1094x; 1.1094x over previous
//
#include <hip/hip_runtime.h>

// ---------------------------------------------------------------------------
// MultiHeadAttention forward, MI355X/gfx950.
// cvt(fp32->bf16, Wq pre-scaled by log2e/8) -> QKV proj (bf16 MFMA, XCD-swz)
// -> V transpose -> flash attn v10 (32x32 MFMA, permlane P-redistribution,
// KV-SPLIT x2 with SEPARATE partial buffers, plain stores, no atomics;
// half-1 partial lives in d_out as scratch) -> norm (sum halves) -> out proj.
// ---------------------------------------------------------------------------

#define DEV static __device__ __forceinline__

typedef unsigned short u16;
typedef __attribute__((ext_vector_type(8))) short short8;
typedef __attribute__((ext_vector_type(4))) float f32x4;
typedef __attribute__((ext_vector_type(16))) float f32x16;
typedef __attribute__((ext_vector_type(4))) unsigned short ushort4v;
typedef __attribute__((ext_vector_type(4))) unsigned int uint4v;

#define SEQ   2048
#define BATCH 2
#define DM    1024
#define NH    16
#define DKH   64
#define MROWS (SEQ*BATCH)   // 4096

DEV u16 f2bf(float f) {            // RNE
  union { float f; unsigned int u; } v; v.f = f;
  unsigned int u = v.u;
  return (u16)((u + 0x7FFFu + ((u >> 16) & 1u)) >> 16);
}

DEV unsigned int cvtpk_bf16(float lo, float hi) {  // dword = bf16(hi)<<16 | bf16(lo), RNE
  unsigned int r;
  asm("v_cvt_pk_bf16_f32 %0, %1, %2" : "=v"(r) : "v"(lo), "v"(hi));
  return r;
}

// v_permlane32_swap_b32 a, b: swaps a.lanes[32:63] <-> b.lanes[0:31]
DEV void permswap(unsigned int& a, unsigned int& b) {
  asm volatile("v_permlane32_swap_b32 %0, %1" : "+v"(a), "+v"(b));
}

#if __has_builtin(__builtin_amdgcn_exp2f)
#define EXP2(x) __builtin_amdgcn_exp2f(x)
#else
#define EXP2(x) exp2f(x)
#endif

// async global->LDS, 16B per lane. LDS dest is wave-uniform base + lane*16.
DEV void async16(const void* g, void* l) {
  __builtin_amdgcn_global_load_lds(
      (const __attribute__((address_space(1))) unsigned int*)g,
      (__attribute__((address_space(3))) unsigned int*)l, 16, 0, 0);
}

// ---------------------------------------------------------------------------
// fp32 -> bf16 conversion (grid.y = tensor id; y==7 is the mask-zero scan)
// ---------------------------------------------------------------------------
struct CvtArgs {
  const float* s[8];
  u16* d[8];
  int n[8];
  float scale[8];
  int* flag;
};

__global__ __launch_bounds__(256) void cvt_kernel(CvtArgs a) {
  const int t = blockIdx.y;
  const int n = a.n[t];
  const int stride = 1024 * 256 * 4;
  if (t == 7) {   // mask scan
    const float* __restrict__ m = a.s[7];
    int any = 0;
    for (int i = (blockIdx.x * 256 + threadIdx.x) * 4; i < n; i += stride) {
      f32x4 v = *(const f32x4*)&m[i];
      any |= (v[0] != 0.f); any |= (v[1] != 0.f);
      any |= (v[2] != 0.f); any |= (v[3] != 0.f);
    }
    if (any) atomicOr(a.flag, 1);
    return;
  }
  const float* __restrict__ s = a.s[t];
  u16* __restrict__ d = a.d[t];
  const float sc = a.scale[t];
  for (int i = (blockIdx.x * 256 + threadIdx.x) * 4; i < n; i += stride) {
    f32x4 f = *(const f32x4*)&s[i];
    ushort4v o;
    o[0] = f2bf(f[0] * sc); o[1] = f2bf(f[1] * sc);
    o[2] = f2bf(f[2] * sc); o[3] = f2bf(f[3] * sc);
    *(ushort4v*)&d[i] = o;
  }
}

// ---------------------------------------------------------------------------
// GEMM: C[M,N] = A[M,K] @ W[N,K]^T + bias*bscale.
// Block tile (MT*32) x (NT*32), BK=64, 4 waves in 2x2.
// ---------------------------------------------------------------------------
template <int MT, int NT, typename OutT>
DEV void gemm_body(const u16* __restrict__ A,
                   const u16* __restrict__ W,
                   const float* __restrict__ bias, float bscale,
                   OutT* __restrict__ C,
                   u16* As, u16* Bs,
                   int M, int N, int K, int m0, int n0) {
  const int tid = threadIdx.x;
  const int lane = tid & 63;
  const int wid = tid >> 6;
  const int wr = wid >> 1, wc = wid & 1;
  const int sr = lane & 15, g = lane >> 4;

  f32x4 acc[MT][NT] = {};

  const int arow = tid >> 3;          // 0..31
  const int acol = (tid & 7) * 8;     // elem col within 64
  const size_t abase = (size_t)(m0 + arow) * K + acol;
  const size_t bbase = (size_t)(n0 + arow) * K + acol;

  for (int kt = 0; kt < K; kt += 64) {
#pragma unroll
    for (int j = 0; j < MT; ++j)
      async16(A + abase + (size_t)j * 32 * K + kt, (char*)As + j * 4096 + wid * 1024);
#pragma unroll
    for (int j = 0; j < NT; ++j)
      async16(W + bbase + (size_t)j * 32 * K + kt, (char*)Bs + j * 4096 + wid * 1024);
    __syncthreads();
#pragma unroll
    for (int kk = 0; kk < 2; ++kk) {
      short8 af[MT], bf[NT];
#pragma unroll
      for (int mt = 0; mt < MT; ++mt)
        af[mt] = *(const short8*)&As[(wr * MT * 16 + mt * 16 + sr) * 64 + kk * 32 + g * 8];
#pragma unroll
      for (int nt = 0; nt < NT; ++nt)
        bf[nt] = *(const short8*)&Bs[(wc * NT * 16 + nt * 16 + sr) * 64 + kk * 32 + g * 8];
#pragma unroll
      for (int mt = 0; mt < MT; ++mt)
#pragma unroll
        for (int nt = 0; nt < NT; ++nt)
          acc[mt][nt] = __builtin_amdgcn_mfma_f32_16x16x32_bf16(af[mt], bf[nt], acc[mt][nt], 0, 0, 0);
    }
    __syncthreads();
  }

  // C/D layout: row=(lane>>4)*4+reg, col=lane&15  [m89-verified]
#pragma unroll
  for (int nt = 0; nt < NT; ++nt) {
    const int col = n0 + wc * NT * 16 + nt * 16 + sr;
    const float bv = bias[col] * bscale;
#pragma unroll
    for (int mt = 0; mt < MT; ++mt) {
#pragma unroll
      for (int r = 0; r < 4; ++r) {
        const int row = m0 + wr * MT * 16 + mt * 16 + g * 4 + r;
        const float val = acc[mt][nt][r] + bv;
        if constexpr (sizeof(OutT) == 2)
          C[(size_t)row * N + col] = f2bf(val);
        else
          C[(size_t)row * N + col] = val;
      }
    }
  }
}

struct GemmPtrs {
  const u16* A[3];
  const u16* W[3];
  const float* bias[3];
  float bscale[3];
  u16* C[3];
};

__global__ __launch_bounds__(256) void gemm_qkv_kernel(GemmPtrs p, int M, int N, int K) {
  __shared__ u16 As[128 * 64];
  __shared__ u16 Bs[128 * 64];
  const int z = blockIdx.z;
  const int fl = blockIdx.x + 32 * blockIdx.y;
  const int virt = (fl & 7) * 32 + (fl >> 3);
  const int mb = virt >> 3, nb = virt & 7;
  gemm_body<4, 4, u16>(p.A[z], p.W[z], p.bias[z], p.bscale[z], p.C[z], As, Bs,
                       M, N, K, mb * 128, nb * 128);
}

__global__ __launch_bounds__(256) void gemm_f32_kernel(const u16* __restrict__ A,
                                                       const u16* __restrict__ W,
                                                       const float* __restrict__ bias,
                                                       float* __restrict__ C,
                                                       int M, int N, int K) {
  __shared__ u16 As[64 * 64];
  __shared__ u16 Bs[128 * 64];
  const int fl = blockIdx.x + 64 * blockIdx.y;
  const int virt = (fl & 7) * 64 + (fl >> 3);
  const int mb = virt >> 3, nb = virt & 7;
  gemm_body<2, 4, float>(A, W, bias, 1.0f, C, As, Bs, M, N, K,
                         mb * 64, nb * 128);
}

// ---------------------------------------------------------------------------
// V transpose: Vh (S,B,D) bf16 -> VT[bh][dk][t]  (shape [32][64][2048])
// ---------------------------------------------------------------------------
__global__ __launch_bounds__(256) void vtrans_kernel(const u16* __restrict__ Vh,
                                                     u16* __restrict__ VT) {
  __shared__ u16 tl[4096];   // [t][dk] linear
  const int tid = threadIdx.x;
  const int w = tid >> 6;
  const int t0 = blockIdx.x * 64;
  const int bh = blockIdx.y;
  const int b = bh >> 4, h = bh & 15;
  const int str = tid >> 3;
  const int scc = (tid & 7) * 8;
#pragma unroll
  for (int it = 0; it < 2; ++it)
    async16(Vh + (size_t)((t0 + str + it * 32) * 2 + b) * 1024 + h * 64 + scc,
            (char*)tl + it * 4096 + w * 1024);
  __syncthreads();
  const int dk = tid >> 2;
  const int t4 = (tid & 3) * 16;
  short8 ov[2];
#pragma unroll
  for (int half = 0; half < 2; ++half)
#pragma unroll
    for (int j = 0; j < 8; ++j)
      ov[half][j] = (short)tl[(t4 + half * 8 + j) * 64 + dk];
  u16* dst = VT + (size_t)(bh * 64 + dk) * 2048 + t0 + t4;
  *(short8*)dst = ov[0];
  *(short8*)(dst + 8) = ov[1];
}

// ---------------------------------------------------------------------------
// Flash attention v10: 32x32x16 MFMA, KV-split x2, NO atomics.  Grid 1024
// flat (XCD-swizzled), 256 thr = 4 waves (4 blk/CU -> 4 waves/SIMD), wave
// owns 32 q-rows, t-range = half*1024..+1024 (16 tiles).  Single-tile dbuf
// staging (32KB LDS).  Swapped QK^T (A=K, B=Q, 0.125*log2e in Wq); C/D
// col=q=lane&31, row t=(r&3)+8*(r>>2)+4*(lane>>5) [m74/m101].  P->PV A-frags
// via cvt_pk + permswap (verified r8).  No-max softmax -> partials ADDITIVE:
// each half PLAIN-STORES its own O/l buffer (every element written once).
// ---------------------------------------------------------------------------
__global__ __launch_bounds__(256, 4) void attn10_kernel(const u16* __restrict__ Q,
                                                        const u16* __restrict__ K,
                                                        const u16* __restrict__ VT,
                                                        const float* __restrict__ mask,
                                                        const int* __restrict__ maskflag,
                                                        float* __restrict__ O0,
                                                        float* __restrict__ O1,
                                                        float* __restrict__ l0,
                                                        float* __restrict__ l1) {
  __shared__ u16 Kl[2][4096];   // [t 0..63][d 0..63], 128B rows, XOR-swizzled
  __shared__ u16 Vl[2][4096];   // [d 0..63][t 0..63], 128B rows, XOR-swizzled

  const int tid = threadIdx.x;
  const int lane = tid & 63;
  const int w = tid >> 6;
  const int ln = lane & 31;     // col within 32-block
  const int hi = lane >> 5;     // lane half
  const int sw = (ln & 7) << 4;

  // XCD swizzle: 1024 = 8 XCDs x 128; each XCD gets 4 bh x (2 half x 16 qi)
  const int flat = blockIdx.x;
  const int virt = ((flat & 7) << 7) | (flat >> 3);
  const int bh = virt >> 5;
  const int half = (virt >> 4) & 1;
  const int qi = virt & 15;
  const int q0 = qi * 128 + w * 32;
  const int tbase = half * 1024;
  const int b = bh >> 4, h = bh & 15;
  const int usemask = *maskflag;

  float* __restrict__ Oh = half ? O1 : O0;
  float* __restrict__ lh = half ? l1 : l0;

  const u16* Qb = Q + b * DM + h * DKH;
  const u16* Kb = K + b * DM + h * DKH;
  const u16* VTb = VT + (size_t)bh * 64 * 2048;

  // Q fragments (B-operand 32x32x16: col n=q=ln, k = ks*16 + hi*8 + j)
  short8 aq[4];
#pragma unroll
  for (int ks = 0; ks < 4; ++ks)
    aq[ks] = *(const short8*)&Qb[(size_t)(q0 + ln) * 2048 + ks * 16 + hi * 8];

  f32x16 acc[2] = {};
  float l_ = 0.f;
  const float L2E = 1.44269504088896f;

  const int strow = tid >> 3;                                   // 0..31
  const int scb = (((tid & 7) * 16) ^ ((strow & 7) << 4)) >> 1; // pre-swizzled col (elems)

  auto STAGE = [&](int nb, int t0n) {
#pragma unroll
    for (int it = 0; it < 2; ++it) {
      async16(Kb + (size_t)(t0n + strow + it * 32) * 2048 + scb,
              (char*)&Kl[nb][0] + it * 4096 + w * 1024);
      async16(VTb + (size_t)(strow + it * 32) * 2048 + t0n + scb,
              (char*)&Vl[nb][0] + it * 4096 + w * 1024);
    }
  };

  STAGE(0, tbase);
  __syncthreads();
  int cur = 0;

  for (int t0 = tbase; t0 < tbase + 1024; t0 += 64) {
    if (t0 + 64 < tbase + 1024) STAGE(cur ^ 1, t0 + 64);

    // K fragments (A-operand: row t = tb*32+ln, k = d = ks*16+hi*8+j)
    short8 kf[2][4];
#pragma unroll
    for (int tb = 0; tb < 2; ++tb)
#pragma unroll
      for (int ks = 0; ks < 4; ++ks)
        kf[tb][ks] = *(const short8*)((const char*)&Kl[cur][0] +
                                      (tb * 32 + ln) * 128 + ((ks * 32 + hi * 16) ^ sw));

    // S'^T (log2 units): 2 blocks of 32t x 32q
    f32x16 sc[2] = {};
    __builtin_amdgcn_s_setprio(1);
#pragma unroll
    for (int tb = 0; tb < 2; ++tb)
#pragma unroll
      for (int ks = 0; ks < 4; ++ks)
        sc[tb] = __builtin_amdgcn_mfma_f32_32x32x16_bf16(kf[tb][ks], aq[ks], sc[tb], 0, 0, 0);
    __builtin_amdgcn_s_setprio(0);

    // V^T fragments (B-operand: col n=d=db*32+ln, k = t = ks*16+hi*8+j)
    short8 vf[2][4];
#pragma unroll
    for (int db = 0; db < 2; ++db)
#pragma unroll
      for (int ks = 0; ks < 4; ++ks)
        vf[db][ks] = *(const short8*)((const char*)&Vl[cur][0] +
                                      (db * 32 + ln) * 128 + ((ks * 32 + hi * 16) ^ sw));

    // no-max softmax + in-register P redistribution (cvt_pk + permlane32_swap)
    short8 pa[4];
    float rs = 0.f;
#pragma unroll
    for (int tb = 0; tb < 2; ++tb) {
      float p[16];
#pragma unroll
      for (int r = 0; r < 16; ++r) {
        float xv = sc[tb][r];
        if (usemask)
          xv = __builtin_fmaf(
              mask[(size_t)(q0 + ln) * SEQ + t0 + tb * 32 + (r & 3) + 8 * (r >> 2) + 4 * hi],
              L2E, xv);
        p[r] = EXP2(xv);
        rs += p[r];
      }
#pragma unroll
      for (int ksl = 0; ksl < 2; ++ksl) {
        unsigned int c0 = cvtpk_bf16(p[8 * ksl + 0], p[8 * ksl + 1]);  // (t0,t1 | t4,t5)
        unsigned int c1 = cvtpk_bf16(p[8 * ksl + 2], p[8 * ksl + 3]);  // (t2,t3 | t6,t7)
        unsigned int c4 = cvtpk_bf16(p[8 * ksl + 4], p[8 * ksl + 5]);  // (t8,t9 | t12,t13)
        unsigned int c5 = cvtpk_bf16(p[8 * ksl + 6], p[8 * ksl + 7]);  // (t10,t11|t14,t15)
        permswap(c0, c4);   // c0 -> dword0; c4 -> dword2
        permswap(c1, c5);   // c1 -> dword1; c5 -> dword3
        union { uint4v u; short8 s; } cc;
        cc.u[0] = c0; cc.u[1] = c1; cc.u[2] = c4; cc.u[3] = c5;
        pa[tb * 2 + ksl] = cc.s;
      }
    }
    l_ += rs;

    // PV: O[q][d] += P[q][t] V[t][d]
    __builtin_amdgcn_s_setprio(1);
#pragma unroll
    for (int ks = 0; ks < 4; ++ks)
#pragma unroll
      for (int db = 0; db < 2; ++db)
        acc[db] = __builtin_amdgcn_mfma_f32_32x32x16_bf16(pa[ks], vf[db][ks], acc[db], 0, 0, 0);
    __builtin_amdgcn_s_setprio(0);
    __syncthreads();
    cur ^= 1;
  }

  // partial epilogue: combine lane halves of l, plain stores (no collisions)
  l_ += __shfl_xor(l_, 32);
  if (lane < 32) lh[bh * 2048 + q0 + ln] = l_;
  const size_t obase = (size_t)b * DM + h * DKH;
#pragma unroll
  for (int db = 0; db < 2; ++db)
#pragma unroll
    for (int r = 0; r < 16; ++r) {
      const int q = q0 + (r & 3) + 8 * (r >> 2) + 4 * hi;
      Oh[(size_t)q * 2048 + obase + db * 32 + ln] = acc[db][r];
    }
}

// ---------------------------------------------------------------------------
// Normalize: AO[i] = bf16((O0[i]+O1[i]) / (l0[row]+l1[row]))
// ---------------------------------------------------------------------------
__global__ __launch_bounds__(256) void norm_kernel(const float* __restrict__ O0,
                                                   const float* __restrict__ O1,
                                                   const float* __restrict__ l0,
                                                   const float* __restrict__ l1,
                                                   u16* __restrict__ AO) {
  const int i4 = (blockIdx.x * 256 + threadIdx.x) * 4;
  const int row = i4 >> 10;          // q*2 + b
  const int col = i4 & 1023;         // h*64 + dk
  const int b = row & 1, q = row >> 1, h = col >> 6;
  const int li = (b * 16 + h) * 2048 + q;
  const float inv = 1.0f / (l0[li] + l1[li]);
  f32x4 o0 = *(const f32x4*)&O0[i4];
  f32x4 o1 = *(const f32x4*)&O1[i4];
  ushort4v out;
  out[0] = f2bf((o0[0] + o1[0]) * inv); out[1] = f2bf((o0[1] + o1[1]) * inv);
  out[2] = f2bf((o0[2] + o1[2]) * inv); out[3] = f2bf((o0[3] + o1[3]) * inv);
  *(ushort4v*)&AO[i4] = out;
}

// ---------------------------------------------------------------------------
// Launch
// ---------------------------------------------------------------------------
extern "C" void kernel_launch(void* const* d_in, const int* in_sizes, int n_in,
                              void* d_out, int out_size, void* d_ws, size_t ws_size,
                              hipStream_t stream) {
  const float* q = (const float*)d_in[0];
  const float* k = (const float*)d_in[1];
  const float* v = (const float*)d_in[2];
  const float* msk = (const float*)d_in[3];
  const float* Wq = (const float*)d_in[4];
  const float* bq = (const float*)d_in[5];
  const float* Wk = (const float*)d_in[6];
  const float* bk = (const float*)d_in[7];
  const float* Wv = (const float*)d_in[8];
  const float* bv = (const float*)d_in[9];
  const float* Wo = (const float*)d_in[10];
  const float* bo = (const float*)d_in[11];
  float* out = (float*)d_out;

  char* ws = (char*)d_ws;
  const size_t SZX = (size_t)MROWS * DM * 2;   // 8 MB bf16 activation
  const size_t SZW = (size_t)DM * DM * 2;      // 2 MB bf16 weight
  u16* qb  = (u16*)(ws + 0 * SZX);
  u16* kb  = (u16*)(ws + 1 * SZX);
  u16* vb  = (u16*)(ws + 2 * SZX);
  u16* Wqb = (u16*)(ws + 3 * SZX + 0 * SZW);
  u16* Wkb = (u16*)(ws + 3 * SZX + 1 * SZW);
  u16* Wvb = (u16*)(ws + 3 * SZX + 2 * SZW);
  u16* Wob = (u16*)(ws + 3 * SZX + 3 * SZW);
  u16* Qh  = (u16*)(ws + 3 * SZX + 4 * SZW + 0 * SZX);
  u16* Kh  = (u16*)(ws + 3 * SZX + 4 * SZW + 1 * SZX);
  u16* Vh  = (u16*)(ws + 3 * SZX + 4 * SZW + 2 * SZX);
  u16* AO  = (u16*)(ws + 3 * SZX + 4 * SZW + 3 * SZX);
  int* flag = (int*)(ws + 7 * SZX + 4 * SZW);
  u16* VTg = qb;                 // reuse qb (dead after gemm_qkv)
  float* O0 = (float*)kb;        // reuse kb+vb: 16 MB, dead after gemm_qkv
  float* O1 = out;               // d_out as scratch; fully rewritten by gemm_f32
  float* l0 = (float*)Wqb;       // dead after gemm_qkv (256 KB needed)
  float* l1 = (float*)Wkb;       // dead after gemm_qkv

  hipMemsetAsync(flag, 0, 4, stream);

  // fold softmax scale AND log2(e) into Wq/bq: S' = (QK^T)/8 * log2e
  const float QS = 0.125f * 1.44269504088896f;

  CvtArgs ca;
  ca.s[0] = q;  ca.d[0] = qb;  ca.n[0] = MROWS * DM; ca.scale[0] = 1.f;
  ca.s[1] = k;  ca.d[1] = kb;  ca.n[1] = MROWS * DM; ca.scale[1] = 1.f;
  ca.s[2] = v;  ca.d[2] = vb;  ca.n[2] = MROWS * DM; ca.scale[2] = 1.f;
  ca.s[3] = Wq; ca.d[3] = Wqb; ca.n[3] = DM * DM;    ca.scale[3] = QS;
  ca.s[4] = Wk; ca.d[4] = Wkb; ca.n[4] = DM * DM;    ca.scale[4] = 1.f;
  ca.s[5] = Wv; ca.d[5] = Wvb; ca.n[5] = DM * DM;    ca.scale[5] = 1.f;
  ca.s[6] = Wo; ca.d[6] = Wob; ca.n[6] = DM * DM;    ca.scale[6] = 1.f;
  ca.s[7] = msk; ca.d[7] = nullptr; ca.n[7] = SEQ * SEQ; ca.scale[7] = 1.f;
  ca.flag = flag;
  cvt_kernel<<<dim3(1024, 8, 1), 256, 0, stream>>>(ca);

  GemmPtrs gp;
  gp.A[0] = qb; gp.W[0] = Wqb; gp.bias[0] = bq; gp.bscale[0] = QS;  gp.C[0] = Qh;
  gp.A[1] = kb; gp.W[1] = Wkb; gp.bias[1] = bk; gp.bscale[1] = 1.f; gp.C[1] = Kh;
  gp.A[2] = vb; gp.W[2] = Wvb; gp.bias[2] = bv; gp.bscale[2] = 1.f; gp.C[2] = Vh;
  gemm_qkv_kernel<<<dim3(32, 8, 3), 256, 0, stream>>>(gp, MROWS, DM, DM);

  vtrans_kernel<<<dim3(32, 32, 1), 256, 0, stream>>>(Vh, VTg);

  attn10_kernel<<<dim3(1024, 1, 1), 256, 0, stream>>>(Qh, Kh, VTg, msk, flag,
                                                      O0, O1, l0, l1);

  norm_kernel<<<dim3(MROWS * DM / 1024, 1, 1), 256, 0, stream>>>(O0, O1, l0, l1, AO);

  gemm_f32_kernel<<<dim3(64, 8, 1), 256, 0, stream>>>(AO, Wob, bo, out, MROWS, DM, DM);
}

// Round 12
// 147.431 us; speedup vs baseline: 1.3141x; 1.1845x over previous
//
#include <hip/hip_runtime.h>

// ---------------------------------------------------------------------------
// MultiHeadAttention forward, MI355X/gfx950.
// cvt(fp32->bf16, Wq pre-scaled by log2e/8) -> QKV proj (bf16 MFMA, 64x128
// tiles, 6 blocks/CU, XCD-swz) -> V transpose -> flash attn v8 (32x32 MFMA,
// permlane P-redistribution, pair-staged KV) -> out proj (XCD-swz).
// ---------------------------------------------------------------------------

#define DEV static __device__ __forceinline__

typedef unsigned short u16;
typedef __attribute__((ext_vector_type(8))) short short8;
typedef __attribute__((ext_vector_type(4))) float f32x4;
typedef __attribute__((ext_vector_type(16))) float f32x16;
typedef __attribute__((ext_vector_type(4))) unsigned short ushort4v;
typedef __attribute__((ext_vector_type(4))) unsigned int uint4v;

#define SEQ   2048
#define BATCH 2
#define DM    1024
#define NH    16
#define DKH   64
#define MROWS (SEQ*BATCH)   // 4096

DEV u16 f2bf(float f) {            // RNE
  union { float f; unsigned int u; } v; v.f = f;
  unsigned int u = v.u;
  return (u16)((u + 0x7FFFu + ((u >> 16) & 1u)) >> 16);
}

DEV unsigned int cvtpk_bf16(float lo, float hi) {  // dword = bf16(hi)<<16 | bf16(lo), RNE
  unsigned int r;
  asm("v_cvt_pk_bf16_f32 %0, %1, %2" : "=v"(r) : "v"(lo), "v"(hi));
  return r;
}

// v_permlane32_swap_b32 a, b: swaps a.lanes[32:63] <-> b.lanes[0:31]
DEV void permswap(unsigned int& a, unsigned int& b) {
  asm volatile("v_permlane32_swap_b32 %0, %1" : "+v"(a), "+v"(b));
}

#if __has_builtin(__builtin_amdgcn_exp2f)
#define EXP2(x) __builtin_amdgcn_exp2f(x)
#else
#define EXP2(x) exp2f(x)
#endif

// async global->LDS, 16B per lane. LDS dest is wave-uniform base + lane*16.
DEV void async16(const void* g, void* l) {
  __builtin_amdgcn_global_load_lds(
      (const __attribute__((address_space(1))) unsigned int*)g,
      (__attribute__((address_space(3))) unsigned int*)l, 16, 0, 0);
}

// ---------------------------------------------------------------------------
// fp32 -> bf16 conversion (grid.y = tensor id; y==7 is the mask-zero scan)
// ---------------------------------------------------------------------------
struct CvtArgs {
  const float* s[8];
  u16* d[8];
  int n[8];
  float scale[8];
  int* flag;
};

__global__ __launch_bounds__(256) void cvt_kernel(CvtArgs a) {
  const int t = blockIdx.y;
  const int n = a.n[t];
  const int stride = 1024 * 256 * 4;
  if (t == 7) {   // mask scan
    const float* __restrict__ m = a.s[7];
    int any = 0;
    for (int i = (blockIdx.x * 256 + threadIdx.x) * 4; i < n; i += stride) {
      f32x4 v = *(const f32x4*)&m[i];
      any |= (v[0] != 0.f); any |= (v[1] != 0.f);
      any |= (v[2] != 0.f); any |= (v[3] != 0.f);
    }
    if (any) atomicOr(a.flag, 1);
    return;
  }
  const float* __restrict__ s = a.s[t];
  u16* __restrict__ d = a.d[t];
  const float sc = a.scale[t];
  for (int i = (blockIdx.x * 256 + threadIdx.x) * 4; i < n; i += stride) {
    f32x4 f = *(const f32x4*)&s[i];
    ushort4v o;
    o[0] = f2bf(f[0] * sc); o[1] = f2bf(f[1] * sc);
    o[2] = f2bf(f[2] * sc); o[3] = f2bf(f[3] * sc);
    *(ushort4v*)&d[i] = o;
  }
}

// ---------------------------------------------------------------------------
// GEMM: C[M,N] = A[M,K] @ W[N,K]^T + bias*bscale.
// Block tile (MT*32) x (NT*32), BK=64, 4 waves in 2x2.
// ---------------------------------------------------------------------------
template <int MT, int NT, typename OutT>
DEV void gemm_body(const u16* __restrict__ A,
                   const u16* __restrict__ W,
                   const float* __restrict__ bias, float bscale,
                   OutT* __restrict__ C,
                   u16* As, u16* Bs,
                   int M, int N, int K, int m0, int n0) {
  const int tid = threadIdx.x;
  const int lane = tid & 63;
  const int wid = tid >> 6;
  const int wr = wid >> 1, wc = wid & 1;
  const int sr = lane & 15, g = lane >> 4;

  f32x4 acc[MT][NT] = {};

  const int arow = tid >> 3;          // 0..31
  const int acol = (tid & 7) * 8;     // elem col within 64
  const size_t abase = (size_t)(m0 + arow) * K + acol;
  const size_t bbase = (size_t)(n0 + arow) * K + acol;

  for (int kt = 0; kt < K; kt += 64) {
#pragma unroll
    for (int j = 0; j < MT; ++j)
      async16(A + abase + (size_t)j * 32 * K + kt, (char*)As + j * 4096 + wid * 1024);
#pragma unroll
    for (int j = 0; j < NT; ++j)
      async16(W + bbase + (size_t)j * 32 * K + kt, (char*)Bs + j * 4096 + wid * 1024);
    __syncthreads();
#pragma unroll
    for (int kk = 0; kk < 2; ++kk) {
      short8 af[MT], bf[NT];
#pragma unroll
      for (int mt = 0; mt < MT; ++mt)
        af[mt] = *(const short8*)&As[(wr * MT * 16 + mt * 16 + sr) * 64 + kk * 32 + g * 8];
#pragma unroll
      for (int nt = 0; nt < NT; ++nt)
        bf[nt] = *(const short8*)&Bs[(wc * NT * 16 + nt * 16 + sr) * 64 + kk * 32 + g * 8];
#pragma unroll
      for (int mt = 0; mt < MT; ++mt)
#pragma unroll
        for (int nt = 0; nt < NT; ++nt)
          acc[mt][nt] = __builtin_amdgcn_mfma_f32_16x16x32_bf16(af[mt], bf[nt], acc[mt][nt], 0, 0, 0);
    }
    __syncthreads();
  }

  // C/D layout: row=(lane>>4)*4+reg, col=lane&15  [m89-verified]
#pragma unroll
  for (int nt = 0; nt < NT; ++nt) {
    const int col = n0 + wc * NT * 16 + nt * 16 + sr;
    const float bv = bias[col] * bscale;
#pragma unroll
    for (int mt = 0; mt < MT; ++mt) {
#pragma unroll
      for (int r = 0; r < 4; ++r) {
        const int row = m0 + wr * MT * 16 + mt * 16 + g * 4 + r;
        const float val = acc[mt][nt][r] + bv;
        if constexpr (sizeof(OutT) == 2)
          C[(size_t)row * N + col] = f2bf(val);
        else
          C[(size_t)row * N + col] = val;
      }
    }
  }
}

struct GemmPtrs {
  const u16* A[3];
  const u16* W[3];
  const float* bias[3];
  float bscale[3];
  u16* C[3];
};

// 64x128 tiles: grid 64x8x3 = 1536 blocks = 6 blocks/CU (24 KB LDS) —
// 2x the block-level overlap to hide synchronous staging latency.
__global__ __launch_bounds__(256) void gemm_qkv_kernel(GemmPtrs p, int M, int N, int K) {
  __shared__ u16 As[64 * 64];
  __shared__ u16 Bs[128 * 64];
  const int z = blockIdx.z;
  const int fl = blockIdx.x + 64 * blockIdx.y;
  const int virt = (fl & 7) * 64 + (fl >> 3);
  const int mb = virt >> 3, nb = virt & 7;
  gemm_body<2, 4, u16>(p.A[z], p.W[z], p.bias[z], p.bscale[z], p.C[z], As, Bs,
                       M, N, K, mb * 64, nb * 128);
}

__global__ __launch_bounds__(256) void gemm_f32_kernel(const u16* __restrict__ A,
                                                       const u16* __restrict__ W,
                                                       const float* __restrict__ bias,
                                                       float* __restrict__ C,
                                                       int M, int N, int K) {
  __shared__ u16 As[64 * 64];
  __shared__ u16 Bs[128 * 64];
  const int fl = blockIdx.x + 64 * blockIdx.y;
  const int virt = (fl & 7) * 64 + (fl >> 3);
  const int mb = virt >> 3, nb = virt & 7;
  gemm_body<2, 4, float>(A, W, bias, 1.0f, C, As, Bs, M, N, K,
                         mb * 64, nb * 128);
}

// ---------------------------------------------------------------------------
// V transpose: Vh (S,B,D) bf16 -> VT[bh][dk][t]  (shape [32][64][2048])
// ---------------------------------------------------------------------------
__global__ __launch_bounds__(256) void vtrans_kernel(const u16* __restrict__ Vh,
                                                     u16* __restrict__ VT) {
  __shared__ u16 tl[4096];   // [t][dk] linear
  const int tid = threadIdx.x;
  const int w = tid >> 6;
  const int t0 = blockIdx.x * 64;
  const int bh = blockIdx.y;
  const int b = bh >> 4, h = bh & 15;
  const int str = tid >> 3;
  const int scc = (tid & 7) * 8;
#pragma unroll
  for (int it = 0; it < 2; ++it)
    async16(Vh + (size_t)((t0 + str + it * 32) * 2 + b) * 1024 + h * 64 + scc,
            (char*)tl + it * 4096 + w * 1024);
  __syncthreads();
  const int dk = tid >> 2;
  const int t4 = (tid & 3) * 16;
  short8 ov[2];
#pragma unroll
  for (int half = 0; half < 2; ++half)
#pragma unroll
    for (int j = 0; j < 8; ++j)
      ov[half][j] = (short)tl[(t4 + half * 8 + j) * 64 + dk];
  u16* dst = VT + (size_t)(bh * 64 + dk) * 2048 + t0 + t4;
  *(short8*)dst = ov[0];
  *(short8*)(dst + 8) = ov[1];
}

// ---------------------------------------------------------------------------
// Flash attention v8 (round-9 best): 32x32x16 MFMA, pair-staged KV.  Grid 512
// flat (XCD-swizzled), 256 thr = 4 waves, wave owns 32 q-rows.  TWO 64-row
// KV tiles staged per barrier (4 LDS buffers, 64 KB); both processed between
// barriers for ILP.  Swapped QK^T (A=K, B=Q, 0.125*log2e in Wq); C/D col=q=
// lane&31, row t=(r&3)+8*(r>>2)+4*(lane>>5) [m74/m101].  P->PV A-frags via
// cvt_pk + permswap (verified r8).  No-max softmax, l reduced at end.
// ---------------------------------------------------------------------------
__global__ __launch_bounds__(256, 2) void attn8_kernel(const u16* __restrict__ Q,
                                                       const u16* __restrict__ K,
                                                       const u16* __restrict__ VT,
                                                       const float* __restrict__ mask,
                                                       const int* __restrict__ maskflag,
                                                       u16* __restrict__ O) {
  __shared__ u16 Kl[2][2][4096];   // [buf][subtile][t 0..63][d 0..63], swizzled
  __shared__ u16 Vl[2][2][4096];   // [buf][subtile][d 0..63][t 0..63], swizzled

  const int tid = threadIdx.x;
  const int lane = tid & 63;
  const int w = tid >> 6;
  const int ln = lane & 31;     // col within 32-block
  const int hi = lane >> 5;     // lane half
  const int sw = (ln & 7) << 4;

  // T1: cluster the 16 q-blocks of each bh on one XCD (512 = 8 XCDs x 64)
  const int flat = blockIdx.x;
  const int virt = ((flat & 7) << 6) | (flat >> 3);
  const int qi = virt & 15;
  const int bh = virt >> 4;
  const int q0 = qi * 128 + w * 32;
  const int b = bh >> 4, h = bh & 15;
  const int usemask = *maskflag;

  const u16* Qb = Q + b * DM + h * DKH;
  const u16* Kb = K + b * DM + h * DKH;
  const u16* VTb = VT + (size_t)bh * 64 * 2048;

  // Q fragments (B-operand 32x32x16: col n=q=ln, k = ks*16 + hi*8 + j)
  short8 aq[4];
#pragma unroll
  for (int ks = 0; ks < 4; ++ks)
    aq[ks] = *(const short8*)&Qb[(size_t)(q0 + ln) * 2048 + ks * 16 + hi * 8];

  f32x16 acc[2] = {};
  float l_ = 0.f;
  const float L2E = 1.44269504088896f;

  const int strow = tid >> 3;                                   // 0..31
  const int scb = (((tid & 7) * 16) ^ ((strow & 7) << 4)) >> 1; // pre-swizzled col (elems)

  auto STAGE = [&](int nb, int t0n) {   // stages rows [t0n, t0n+128)
#pragma unroll
    for (int st = 0; st < 2; ++st)
#pragma unroll
      for (int it = 0; it < 2; ++it) {
        async16(Kb + (size_t)(t0n + st * 64 + strow + it * 32) * 2048 + scb,
                (char*)&Kl[nb][st][0] + it * 4096 + w * 1024);
        async16(VTb + (size_t)(strow + it * 32) * 2048 + t0n + st * 64 + scb,
                (char*)&Vl[nb][st][0] + it * 4096 + w * 1024);
      }
  };

  STAGE(0, 0);
  __syncthreads();
  int cur = 0;

  for (int tp = 0; tp < SEQ; tp += 128) {
    if (tp + 128 < SEQ) STAGE(cur ^ 1, tp + 128);

#pragma unroll
    for (int st = 0; st < 2; ++st) {
      const int t0 = tp + st * 64;

      // K fragments (A-operand: row t = tb*32+ln, k = d = ks*16+hi*8+j)
      short8 kf[2][4];
#pragma unroll
      for (int tb = 0; tb < 2; ++tb)
#pragma unroll
        for (int ks = 0; ks < 4; ++ks)
          kf[tb][ks] = *(const short8*)((const char*)&Kl[cur][st][0] +
                                        (tb * 32 + ln) * 128 + ((ks * 32 + hi * 16) ^ sw));

      // S'^T (log2 units): 2 blocks of 32t x 32q
      f32x16 sc[2] = {};
      __builtin_amdgcn_s_setprio(1);
#pragma unroll
      for (int tb = 0; tb < 2; ++tb)
#pragma unroll
        for (int ks = 0; ks < 4; ++ks)
          sc[tb] = __builtin_amdgcn_mfma_f32_32x32x16_bf16(kf[tb][ks], aq[ks], sc[tb], 0, 0, 0);
      __builtin_amdgcn_s_setprio(0);

      // V^T fragments (B-operand: col n=d=db*32+ln, k = t = ks*16+hi*8+j)
      short8 vf[2][4];
#pragma unroll
      for (int db = 0; db < 2; ++db)
#pragma unroll
        for (int ks = 0; ks < 4; ++ks)
          vf[db][ks] = *(const short8*)((const char*)&Vl[cur][st][0] +
                                        (db * 32 + ln) * 128 + ((ks * 32 + hi * 16) ^ sw));

      // no-max softmax + in-register P redistribution (cvt_pk + permlane32_swap)
      short8 pa[4];
      float rs = 0.f;
#pragma unroll
      for (int tb = 0; tb < 2; ++tb) {
        float p[16];
#pragma unroll
        for (int r = 0; r < 16; ++r) {
          float xv = sc[tb][r];
          if (usemask)
            xv = __builtin_fmaf(
                mask[(size_t)(q0 + ln) * SEQ + t0 + tb * 32 + (r & 3) + 8 * (r >> 2) + 4 * hi],
                L2E, xv);
          p[r] = EXP2(xv);
          rs += p[r];
        }
#pragma unroll
        for (int ksl = 0; ksl < 2; ++ksl) {
          unsigned int c0 = cvtpk_bf16(p[8 * ksl + 0], p[8 * ksl + 1]);  // (t0,t1 | t4,t5)
          unsigned int c1 = cvtpk_bf16(p[8 * ksl + 2], p[8 * ksl + 3]);  // (t2,t3 | t6,t7)
          unsigned int c4 = cvtpk_bf16(p[8 * ksl + 4], p[8 * ksl + 5]);  // (t8,t9 | t12,t13)
          unsigned int c5 = cvtpk_bf16(p[8 * ksl + 6], p[8 * ksl + 7]);  // (t10,t11|t14,t15)
          permswap(c0, c4);   // c0 -> dword0; c4 -> dword2
          permswap(c1, c5);   // c1 -> dword1; c5 -> dword3
          union { uint4v u; short8 s; } cc;
          cc.u[0] = c0; cc.u[1] = c1; cc.u[2] = c4; cc.u[3] = c5;
          pa[tb * 2 + ksl] = cc.s;
        }
      }
      l_ += rs;

      // PV: O[q][d] += P[q][t] V[t][d]
      __builtin_amdgcn_s_setprio(1);
#pragma unroll
      for (int ks = 0; ks < 4; ++ks)
#pragma unroll
        for (int db = 0; db < 2; ++db)
          acc[db] = __builtin_amdgcn_mfma_f32_32x32x16_bf16(pa[ks], vf[db][ks], acc[db], 0, 0, 0);
      __builtin_amdgcn_s_setprio(0);
    }

    __syncthreads();
    cur ^= 1;
  }

  // final l reduction (halves) + normalize + write
  l_ += __shfl_xor(l_, 32);
  const float linv = 1.f / l_;
  float lb[16];
#pragma unroll
  for (int r = 0; r < 16; ++r)
    lb[r] = __shfl(linv, (r & 3) + 8 * (r >> 2) + 4 * hi);
  const size_t obase = (size_t)b * DM + h * DKH;
#pragma unroll
  for (int db = 0; db < 2; ++db)
#pragma unroll
    for (int r = 0; r < 16; ++r) {
      const int q = q0 + (r & 3) + 8 * (r >> 2) + 4 * hi;
      O[(size_t)q * 2048 + obase + db * 32 + ln] = f2bf(acc[db][r] * lb[r]);
    }
}

// ---------------------------------------------------------------------------
// Launch
// ---------------------------------------------------------------------------
extern "C" void kernel_launch(void* const* d_in, const int* in_sizes, int n_in,
                              void* d_out, int out_size, void* d_ws, size_t ws_size,
                              hipStream_t stream) {
  const float* q = (const float*)d_in[0];
  const float* k = (const float*)d_in[1];
  const float* v = (const float*)d_in[2];
  const float* msk = (const float*)d_in[3];
  const float* Wq = (const float*)d_in[4];
  const float* bq = (const float*)d_in[5];
  const float* Wk = (const float*)d_in[6];
  const float* bk = (const float*)d_in[7];
  const float* Wv = (const float*)d_in[8];
  const float* bv = (const float*)d_in[9];
  const float* Wo = (const float*)d_in[10];
  const float* bo = (const float*)d_in[11];
  float* out = (float*)d_out;

  char* ws = (char*)d_ws;
  const size_t SZX = (size_t)MROWS * DM * 2;   // 8 MB bf16 activation
  const size_t SZW = (size_t)DM * DM * 2;      // 2 MB bf16 weight
  u16* qb  = (u16*)(ws + 0 * SZX);
  u16* kb  = (u16*)(ws + 1 * SZX);
  u16* vb  = (u16*)(ws + 2 * SZX);
  u16* Wqb = (u16*)(ws + 3 * SZX + 0 * SZW);
  u16* Wkb = (u16*)(ws + 3 * SZX + 1 * SZW);
  u16* Wvb = (u16*)(ws + 3 * SZX + 2 * SZW);
  u16* Wob = (u16*)(ws + 3 * SZX + 3 * SZW);
  u16* Qh  = (u16*)(ws + 3 * SZX + 4 * SZW + 0 * SZX);
  u16* Kh  = (u16*)(ws + 3 * SZX + 4 * SZW + 1 * SZX);
  u16* Vh  = (u16*)(ws + 3 * SZX + 4 * SZW + 2 * SZX);
  u16* AO  = (u16*)(ws + 3 * SZX + 4 * SZW + 3 * SZX);
  int* flag = (int*)(ws + 7 * SZX + 4 * SZW);
  u16* VTg = qb;   // reuse qb (dead after gemm_qkv)

  hipMemsetAsync(flag, 0, 4, stream);

  // fold softmax scale AND log2(e) into Wq/bq: S' = (QK^T)/8 * log2e
  const float QS = 0.125f * 1.44269504088896f;

  CvtArgs ca;
  ca.s[0] = q;  ca.d[0] = qb;  ca.n[0] = MROWS * DM; ca.scale[0] = 1.f;
  ca.s[1] = k;  ca.d[1] = kb;  ca.n[1] = MROWS * DM; ca.scale[1] = 1.f;
  ca.s[2] = v;  ca.d[2] = vb;  ca.n[2] = MROWS * DM; ca.scale[2] = 1.f;
  ca.s[3] = Wq; ca.d[3] = Wqb; ca.n[3] = DM * DM;    ca.scale[3] = QS;
  ca.s[4] = Wk; ca.d[4] = Wkb; ca.n[4] = DM * DM;    ca.scale[4] = 1.f;
  ca.s[5] = Wv; ca.d[5] = Wvb; ca.n[5] = DM * DM;    ca.scale[5] = 1.f;
  ca.s[6] = Wo; ca.d[6] = Wob; ca.n[6] = DM * DM;    ca.scale[6] = 1.f;
  ca.s[7] = msk; ca.d[7] = nullptr; ca.n[7] = SEQ * SEQ; ca.scale[7] = 1.f;
  ca.flag = flag;
  cvt_kernel<<<dim3(1024, 8, 1), 256, 0, stream>>>(ca);

  GemmPtrs gp;
  gp.A[0] = qb; gp.W[0] = Wqb; gp.bias[0] = bq; gp.bscale[0] = QS;  gp.C[0] = Qh;
  gp.A[1] = kb; gp.W[1] = Wkb; gp.bias[1] = bk; gp.bscale[1] = 1.f; gp.C[1] = Kh;
  gp.A[2] = vb; gp.W[2] = Wvb; gp.bias[2] = bv; gp.bscale[2] = 1.f; gp.C[2] = Vh;
  gemm_qkv_kernel<<<dim3(64, 8, 3), 256, 0, stream>>>(gp, MROWS, DM, DM);

  vtrans_kernel<<<dim3(32, 32, 1), 256, 0, stream>>>(Vh, VTg);

  attn8_kernel<<<dim3(512, 1, 1), 256, 0, stream>>>(Qh, Kh, VTg, msk, flag, AO);

  gemm_f32_kernel<<<dim3(64, 8, 1), 256, 0, stream>>>(AO, Wob, bo, out, MROWS, DM, DM);
}